// Round 1
// 695.847 us; speedup vs baseline: 1.0017x; 1.0017x over previous
//
#include <hip/hip_runtime.h>

#define BB 500000
#define NN 256
#define AA 64
#define HH 100

typedef short short8 __attribute__((ext_vector_type(8)));
typedef float float4v __attribute__((ext_vector_type(4)));
typedef int   int4v   __attribute__((ext_vector_type(4)));

#define MFMA16(a, b, c) __builtin_amdgcn_mfma_f32_16x16x32_bf16((a), (b), (c), 0, 0, 0)

__device__ __forceinline__ short f2bf(float f) {
    unsigned u = __builtin_bit_cast(unsigned, f);
    u = (u + 0x7fffu + ((u >> 16) & 1u)) >> 16;   // RNE to bf16
    return (short)u;
}
__device__ __forceinline__ short u2bf(unsigned u) {   // same RNE, on raw bits
    u = (u + 0x7fffu + ((u >> 16) & 1u)) >> 16;
    return (short)u;
}

// ---- LDS layout (bytes) ----
// w1T  : short[112][72]   (gate-folded W1^T, k-pad 64->72)
// w2T  : short[112][136]  (W2^T, k-pad 100->128, stride 136)
// w3T  : short[112][136]
// b1p/b2p/b3p : float[112]
// gate : float[64]
// X    : 8 waves x short[32][136]  (single buffer reused across all 4 layers)
#define OFF_W1T   0
#define OFF_W2T   16128
#define OFF_W3T   46592
#define OFF_B1    77056
#define OFF_B2    77504
#define OFF_B3    77952
#define OFF_GATE  78400
#define OFF_X     78656
#define LDS_TOTAL 148288   // 144.8 KiB -> 1 block/CU, 8 waves = 2 waves/SIMD

#define ROWS_PER_TILE 256  // 8 waves x 32 rows
#define NTILES ((BB + ROWS_PER_TILE - 1) / ROWS_PER_TILE)   // 1954

// Load 8 consecutive rows, fully coalesced: one global_load_dwordx4 per row
// (lane i supplies columns 4i..4i+3; 64 lanes x 16B = exactly one 1KB row).
#define LOAD_GROUP(dst, tile, g)                                            \
    {                                                                       \
        int r0_ = (tile) * ROWS_PER_TILE + wave * 32 + (g) * 8;             \
        if (r0_ + 8 <= BB) {                                                \
            const float* q_ = data + (size_t)r0_ * NN + lane * 4;           \
            _Pragma("unroll")                                               \
            for (int r_ = 0; r_ < 8; ++r_)                                  \
                dst[r_] = *(const float4v*)(q_ + (size_t)r_ * NN);          \
        } else {                                                            \
            _Pragma("unroll")                                               \
            for (int r_ = 0; r_ < 8; ++r_) {                                \
                int row_ = r0_ + r_; row_ = row_ < BB ? row_ : BB - 1;      \
                dst[r_] = *(const float4v*)(data + (size_t)row_ * NN + lane * 4); \
            }                                                               \
        }                                                                   \
    }

// In-wave gather: lane e needs column didx[e] = component (c&3) of lane (c>>2).
#define GATHER_GROUP(src, g)                                                \
    {                                                                       \
        _Pragma("unroll")                                                   \
        for (int r_ = 0; r_ < 8; ++r_) {                                    \
            int4v iv_ = __builtin_bit_cast(int4v, src[r_]);                 \
            int g0_ = __builtin_amdgcn_ds_bpermute(baddr, iv_[0]);          \
            int g1_ = __builtin_amdgcn_ds_bpermute(baddr, iv_[1]);          \
            int g2_ = __builtin_amdgcn_ds_bpermute(baddr, iv_[2]);          \
            int g3_ = __builtin_amdgcn_ds_bpermute(baddr, iv_[3]);          \
            int lo_ = c0 ? g1_ : g0_;                                       \
            int hi_ = c0 ? g3_ : g2_;                                       \
            unsigned u_ = (unsigned)(c1 ? hi_ : lo_);                       \
            Xw[((g) * 8 + r_) * 136 + lane] = u2bf(u_);                     \
        }                                                                   \
    }

__global__ void __launch_bounds__(512, 2)
nodal_mlp(const float* __restrict__ data, const float* __restrict__ weights,
          const float* __restrict__ W1, const float* __restrict__ b1,
          const float* __restrict__ W2, const float* __restrict__ b2,
          const float* __restrict__ W3, const float* __restrict__ b3,
          const float* __restrict__ W4, const float* __restrict__ b4,
          const int* __restrict__ didx, const int* __restrict__ edir,
          const int* __restrict__ widx, float* __restrict__ out)
{
    extern __shared__ char smem[];
    short* w1T  = (short*)(smem + OFF_W1T);
    short* w2T  = (short*)(smem + OFF_W2T);
    short* w3T  = (short*)(smem + OFF_W3T);
    float* b1p  = (float*)(smem + OFF_B1);
    float* b2p  = (float*)(smem + OFF_B2);
    float* b3p  = (float*)(smem + OFF_B3);
    float* gate = (float*)(smem + OFF_GATE);

    const int tid  = threadIdx.x;
    const int wave = tid >> 6;    // 0..7
    const int lane = tid & 63;
    const int m    = lane & 15;   // MFMA A-row / C-col
    const int quad = lane >> 4;   // MFMA k-group / C row-group

    short* Xw = (short*)(smem + OFF_X) + wave * (32 * 136);

    // ---- one-time staging ----
    if (tid < AA)
        gate[tid] = fmaxf(weights[widx[tid]] * (float)edir[tid], 0.f);
    if (tid < 112) {
        b1p[tid] = (tid < HH) ? b1[tid] : 0.f;
        b2p[tid] = (tid < HH) ? b2[tid] : 0.f;
        b3p[tid] = (tid < HH) ? b3[tid] : 0.f;
    }
    for (int i = tid; i < 112 * 72; i += 512) w1T[i] = 0;
    for (int i = tid; i < 112 * 136; i += 512) { w2T[i] = 0; w3T[i] = 0; }
    // zero X pad cols k in [112,128): read by L2/L3 K-loops, never rewritten
    for (int i = lane; i < 32 * 16; i += 64) {
        int r = i >> 4, k = 112 + (i & 15);
        Xw[r * 136 + k] = 0;
    }
    __syncthreads();
    for (int j = tid; j < AA * HH; j += 512) {        // gate-folded W1^T
        int k = j / HH, n = j - k * HH;
        w1T[n * 72 + k] = f2bf(gate[k] * W1[j]);
    }
    for (int j = tid; j < HH * HH; j += 512) {
        int k = j / HH, n = j - k * HH;
        w2T[n * 136 + k] = f2bf(W2[j]);
        w3T[n * 136 + k] = f2bf(W3[j]);
    }
    __syncthreads();
    // no barriers in main loop: X is wave-private, weights read-only

    // W4 as register B-fragments (only column n==0 non-zero)
    short8 w4f[4];
    #pragma unroll
    for (int ks = 0; ks < 4; ++ks) {
        #pragma unroll
        for (int j = 0; j < 8; ++j) {
            int k = ks * 32 + quad * 8 + j;
            w4f[ks][j] = (m == 0 && k < HH) ? f2bf(W4[k]) : (short)0;
        }
    }
    const float b4v = b4[0];

    // per-lane gather constants (lane == edge index, A == 64)
    const int  cidx  = didx[lane];
    const int  baddr = (cidx >> 2) << 2;   // ds_bpermute byte addr = srcLane*4
    const bool c0    = (cidx & 1) != 0;
    const bool c1    = (cidx & 2) != 0;

    float4v bufA[8], bufB[8];   // 2 x 8 rows double buffer (64 VGPRs)
    int t = (int)blockIdx.x;
    LOAD_GROUP(bufA, t, 0);     // prefetch first group of first tile

    for (; t < NTILES; t += gridDim.x) {
        const int r0 = t * ROWS_PER_TILE + wave * 32;

        // ---- stage gathered X0 (bf16) into cols 0..63, 4 groups of 8 rows,
        //      next group's coalesced row-loads always in flight ----
        LOAD_GROUP(bufB, t, 1);
        GATHER_GROUP(bufA, 0);
        LOAD_GROUP(bufA, t, 2);
        GATHER_GROUP(bufB, 1);
        LOAD_GROUP(bufB, t, 3);
        GATHER_GROUP(bufA, 2);
        {   // issue next tile's first group before the compute phase
            int tn = t + (int)gridDim.x;
            if (tn < NTILES) LOAD_GROUP(bufA, tn, 0);
        }
        GATHER_GROUP(bufB, 3);

        // ---- layer 1: X[32x64] @ W1g[64x112] -> X (relu), 2 subtiles share W reads
        {
            short8 a1[2][2];
            #pragma unroll
            for (int sub = 0; sub < 2; ++sub)
                #pragma unroll
                for (int ks = 0; ks < 2; ++ks)
                    a1[sub][ks] = *(const short8*)(Xw + (sub * 16 + m) * 136 + ks * 32 + quad * 8);
            #pragma unroll
            for (int nt = 0; nt < 7; ++nt) {
                const short* wp = w1T + (nt * 16 + m) * 72 + quad * 8;
                short8 w0 = *(const short8*)(wp);
                short8 w1v = *(const short8*)(wp + 32);
                float bias = b1p[nt * 16 + m];
                #pragma unroll
                for (int sub = 0; sub < 2; ++sub) {
                    float4v c = {0.f, 0.f, 0.f, 0.f};
                    c = MFMA16(a1[sub][0], w0, c);
                    c = MFMA16(a1[sub][1], w1v, c);
                    #pragma unroll
                    for (int i = 0; i < 4; ++i)
                        Xw[(sub * 16 + quad * 4 + i) * 136 + nt * 16 + m] =
                            f2bf(fmaxf(c[i] + bias, 0.f));
                }
            }
        }

        // ---- layers 2 & 3: X @ W -> X (relu), in-place, W reads shared by 2 subtiles
        #pragma unroll
        for (int L = 0; L < 2; ++L) {
            const short* wT = L ? w3T : w2T;
            const float* bp = L ? b3p : b2p;
            short8 a[2][4];
            #pragma unroll
            for (int sub = 0; sub < 2; ++sub)
                #pragma unroll
                for (int ks = 0; ks < 4; ++ks)
                    a[sub][ks] = *(const short8*)(Xw + (sub * 16 + m) * 136 + ks * 32 + quad * 8);
            #pragma unroll
            for (int nt = 0; nt < 7; ++nt) {
                const short* wp = wT + (nt * 16 + m) * 136 + quad * 8;
                short8 wf[4];
                #pragma unroll
                for (int ks = 0; ks < 4; ++ks)
                    wf[ks] = *(const short8*)(wp + ks * 32);
                float bias = bp[nt * 16 + m];
                #pragma unroll
                for (int sub = 0; sub < 2; ++sub) {
                    float4v c = {0.f, 0.f, 0.f, 0.f};
                    #pragma unroll
                    for (int ks = 0; ks < 4; ++ks)
                        c = MFMA16(a[sub][ks], wf[ks], c);
                    #pragma unroll
                    for (int i = 0; i < 4; ++i)
                        Xw[(sub * 16 + quad * 4 + i) * 136 + nt * 16 + m] =
                            f2bf(fmaxf(c[i] + bias, 0.f));
                }
            }
        }

        // ---- layer 4: X[32x100] . W4 -> out ----
        #pragma unroll
        for (int sub = 0; sub < 2; ++sub) {
            float4v c = {0.f, 0.f, 0.f, 0.f};
            #pragma unroll
            for (int ks = 0; ks < 4; ++ks) {
                short8 a = *(const short8*)(Xw + (sub * 16 + m) * 136 + ks * 32 + quad * 8);
                c = MFMA16(a, w4f[ks], c);
            }
            if (m == 0) {   // C col 0 lives in lanes {0,16,32,48}; rows quad*4+i
                #pragma unroll
                for (int i = 0; i < 4; ++i) {
                    int row = r0 + sub * 16 + quad * 4 + i;
                    if (row < BB) out[row] = c[i] + b4v;
                }
            }
        }
    }
}

extern "C" void kernel_launch(void* const* d_in, const int* in_sizes, int n_in,
                              void* d_out, int out_size, void* d_ws, size_t ws_size,
                              hipStream_t stream) {
    (void)in_sizes; (void)n_in; (void)d_ws; (void)ws_size; (void)out_size;
    const float* data    = (const float*)d_in[0];
    const float* weights = (const float*)d_in[1];
    const float* W1      = (const float*)d_in[2];
    const float* b1      = (const float*)d_in[3];
    const float* W2      = (const float*)d_in[4];
    const float* b2      = (const float*)d_in[5];
    const float* W3      = (const float*)d_in[6];
    const float* b3      = (const float*)d_in[7];
    const float* W4      = (const float*)d_in[8];
    const float* b4      = (const float*)d_in[9];
    const int*   didx    = (const int*)d_in[10];
    const int*   edir    = (const int*)d_in[11];
    const int*   widx    = (const int*)d_in[12];
    float* out = (float*)d_out;

    hipFuncSetAttribute((const void*)nodal_mlp,
                        hipFuncAttributeMaxDynamicSharedMemorySize, LDS_TOTAL);
    nodal_mlp<<<256, 512, LDS_TOTAL, stream>>>(
        data, weights, W1, b1, W2, b2, W3, b3, W4, b4, didx, edir, widx, out);
}